// Round 1
// baseline (12.893 us; speedup 1.0000x reference)
//
#include <hip/hip_runtime.h>

// Problem constants (from reference)
#define X_AXIS 32
#define Y_AXIS 32
#define F_DIM  64
#define N_NODES (X_AXIS * Y_AXIS)   // 1024

// Mathematical reduction:
//   att = softmax(attx, axis=0)  =>  sum_x att[x,y] == 1 for all y
//   node has shape (1,N) -> constant along axis 0
//   out[y] = sum_x node[y]*att[x,y] = node[y]
//   node[x*Y+y] = sum_f W_out[f,x,y] * h[f,x,y]
// => out2d[x,y] = sum_f W_out[f,x,y] * h[f,x,y]
// The attention path (adj, W_pair, a_pair) is algebraically dead.

__global__ void MyGAT_reduced_kernel(const float* __restrict__ h,
                                     const float* __restrict__ W_out,
                                     float* __restrict__ out) {
    const int c = blockIdx.x * blockDim.x + threadIdx.x;  // cell = x*32 + y
    if (c >= N_NODES) return;
    float acc = 0.0f;
#pragma unroll
    for (int f = 0; f < F_DIM; ++f) {
        // h, W_out both laid out [F][X][Y] contiguously: offset f*1024 + c.
        // Consecutive threads -> consecutive addresses at each f: coalesced.
        acc = fmaf(h[f * N_NODES + c], W_out[f * N_NODES + c], acc);
    }
    out[c] = acc;
}

extern "C" void kernel_launch(void* const* d_in, const int* in_sizes, int n_in,
                              void* d_out, int out_size, void* d_ws, size_t ws_size,
                              hipStream_t stream) {
    // setup_inputs() order: h, adj, W_pair, a_pair, W_out
    const float* h     = (const float*)d_in[0];
    // d_in[1] adj, d_in[2] W_pair, d_in[3] a_pair: unused (dead path)
    const float* W_out = (const float*)d_in[4];
    float* out = (float*)d_out;

    MyGAT_reduced_kernel<<<(N_NODES + 255) / 256, 256, 0, stream>>>(h, W_out, out);
}